// Round 1
// baseline (1088.086 us; speedup 1.0000x reference)
//
#include <hip/hip_runtime.h>
#include <cmath>
#include <complex>

// Problem constants (from reference): sr=16000, band 500-7000, order 8 -> 16 poles.
#define NB   32
#define LX   262144
#define PAD  51                      // padlen = 3*max(len(a),len(b)) = 3*17
#define LTOT (LX + 2 * PAD)          // 262246
#define CM   128                     // chunk length
#define NC   ((LTOT + CM - 1) / CM)  // 2049 chunks (last has 102)
#define NP   8                       // conjugate-pair pole count

struct Coeffs {
    double pre[NP], pim[NP];    // poles (Im>0 half)
    double rre[NP], rim[NP];    // 2*residue (conjugate pair folded)
    double pmre[NP], pmim[NP];  // p^CM for the chunk-combine scan
    double c0;                  // direct (FIR) term
};

// u[t] for one filter pass. PASS 0: odd-extended input minus ext[0].
// PASS 1: time-reversed forward output minus its first sample.
template <int PASS>
__device__ __forceinline__ double load_u(const float* __restrict__ x,
                                         const float* __restrict__ yr,
                                         double base, int t) {
    if (PASS == 0) {
        double e;
        if (t < PAD) {
            e = 2.0 * (double)x[0] - (double)x[PAD - t];
        } else if (t < PAD + LX) {
            e = (double)x[t - PAD];
        } else {
            int i = t - (PAD + LX);
            e = 2.0 * (double)x[LX - 1] - (double)x[LX - 2 - i];
        }
        return e - base;
    } else {
        return (double)yr[LTOT - 1 - t] - base;
    }
}

// K1: per-chunk local recurrence from zero state; emit final states.
// f layout: [c][b*NP + i] (coalesced for k_scan).
template <int PASS>
__global__ void k_states(const float* __restrict__ audio,
                         const float* __restrict__ y1,
                         double2* __restrict__ fst, Coeffs C) {
    int c = blockIdx.x * blockDim.x + threadIdx.x;
    int b = blockIdx.y;
    if (c >= NC) return;
    const float* x  = audio + (size_t)b * LX;
    const float* yr = y1 + (size_t)b * LTOT;
    double base = (PASS == 0) ? (2.0 * (double)x[0] - (double)x[PAD])
                              : (double)yr[LTOT - 1];
    int t0 = c * CM;
    int t1 = t0 + CM; if (t1 > LTOT) t1 = LTOT;
    double sre[NP], sim[NP];
#pragma unroll
    for (int i = 0; i < NP; i++) { sre[i] = 0.0; sim[i] = 0.0; }
    for (int t = t0; t < t1; ++t) {
        double u = load_u<PASS>(x, yr, base, t);
#pragma unroll
        for (int i = 0; i < NP; i++) {
            double nre = fma(C.pre[i], sre[i], fma(-C.pim[i], sim[i], C.rre[i] * u));
            double nim = fma(C.pre[i], sim[i], fma( C.pim[i], sre[i], C.rim[i] * u));
            sre[i] = nre; sim[i] = nim;
        }
    }
#pragma unroll
    for (int i = 0; i < NP; i++)
        fst[(size_t)c * (NB * NP) + b * NP + i] = make_double2(sre[i], sim[i]);
}

// K2: 256 threads (one per row x pole); sequential combine across chunks.
// carry[c] = full-recurrence state entering chunk c.
__global__ void k_scan(const double2* __restrict__ fst,
                       double2* __restrict__ carry, Coeffs C) {
    int tid = blockIdx.x * blockDim.x + threadIdx.x;
    if (tid >= NB * NP) return;
    int i = tid % NP;
    double pre = C.pmre[i], pim = C.pmim[i];
    double sre = 0.0, sim = 0.0;
    for (int c = 0; c < NC; c++) {
        carry[(size_t)c * (NB * NP) + tid] = make_double2(sre, sim);
        double2 fc = fst[(size_t)c * (NB * NP) + tid];
        double nre = fma(pre, sre, fma(-pim, sim, fc.x));
        double nim = fma(pre, sim, fma( pim, sre, fc.y));
        sre = nre; sim = nim;
    }
}

// K3: replay chunk with correct incoming state; emit filtered samples.
// PASS 0 -> y1 (float, B x LTOT). PASS 1 -> d_out with reverse+trim mapping.
template <int PASS>
__global__ void k_apply(const float* __restrict__ audio,
                        const float* __restrict__ y1,
                        float* __restrict__ yout,
                        const double2* __restrict__ carry, Coeffs C) {
    int c = blockIdx.x * blockDim.x + threadIdx.x;
    int b = blockIdx.y;
    if (c >= NC) return;
    const float* x  = audio + (size_t)b * LX;
    const float* yr = y1 + (size_t)b * LTOT;
    double base = (PASS == 0) ? (2.0 * (double)x[0] - (double)x[PAD])
                              : (double)yr[LTOT - 1];
    int t0 = c * CM;
    int t1 = t0 + CM; if (t1 > LTOT) t1 = LTOT;
    double sre[NP], sim[NP];
#pragma unroll
    for (int i = 0; i < NP; i++) {
        double2 s0 = carry[(size_t)c * (NB * NP) + b * NP + i];
        sre[i] = s0.x; sim[i] = s0.y;
    }
    for (int t = t0; t < t1; ++t) {
        double u = load_u<PASS>(x, yr, base, t);
        double y = C.c0 * u;
#pragma unroll
        for (int i = 0; i < NP; i++) {
            double nre = fma(C.pre[i], sre[i], fma(-C.pim[i], sim[i], C.rre[i] * u));
            double nim = fma(C.pre[i], sim[i], fma( C.pim[i], sre[i], C.rim[i] * u));
            sre[i] = nre; sim[i] = nim;
            y += nre;
        }
        if (PASS == 0) {
            yout[(size_t)b * LTOT + t] = (float)y;
        } else {
            int j = (LTOT - 1 - PAD) - t;   // reverse + trim padlen
            if (j >= 0 && j < LX) yout[(size_t)b * LX + j] = (float)y;
        }
    }
}

// Host: replicate scipy butter(8, [500,7000]/8000, 'bandpass') pole/zero form,
// then partial-fraction it. All deterministic double math.
static void compute_coeffs(Coeffs& C) {
    using cd = std::complex<double>;
    const int N = 8;
    const double sr = 16000.0, lo = 500.0, hi = 7000.0;
    const double fs = 2.0;
    double w0 = 2.0 * fs * std::tan(M_PI * (2.0 * lo / sr) / fs);
    double w1 = 2.0 * fs * std::tan(M_PI * (2.0 * hi / sr) / fs);
    double bw = w1 - w0;
    double wo = std::sqrt(w0 * w1);
    cd pbp[16];
    for (int k = 0; k < N; k++) {
        int m = -N + 1 + 2 * k;
        cd pl = -std::exp(cd(0.0, M_PI * m / (2.0 * N)));
        pl *= bw / 2.0;
        cd s = std::sqrt(pl * pl - cd(wo * wo, 0.0));
        pbp[k]     = pl + s;
        pbp[k + N] = pl - s;
    }
    double kbp = std::pow(bw, (double)N);
    const double fs2 = 4.0;
    cd pd[16];
    cd denom = 1.0;
    for (int i = 0; i < 16; i++) {
        pd[i] = (cd(fs2, 0.0) + pbp[i]) / (cd(fs2, 0.0) - pbp[i]);
        denom *= (cd(fs2, 0.0) - pbp[i]);
    }
    // zeros: 8 at z=+1 (from z_bp=0), 8 at z=-1 (appended)
    double kd = kbp * std::real(cd(std::pow(fs2, 8.0), 0.0) / denom);
    cd prodp = 1.0;
    for (int i = 0; i < 16; i++) prodp *= pd[i];
    cd c0 = cd(kd, 0.0) / prodp;  // prod(zeros) = (+1)^8 * (-1)^8 = 1
    int n = 0;
    for (int i = 0; i < 16; i++) {
        if (pd[i].imag() <= 0.0) continue;
        cd inv = 1.0 / pd[i];
        cd t1 = cd(1.0, 0.0) - inv;  // zero at +1
        cd t2 = cd(1.0, 0.0) + inv;  // zero at -1
        cd numr = cd(kd, 0.0);
        for (int k = 0; k < 8; k++) numr *= t1;
        for (int k = 0; k < 8; k++) numr *= t2;
        cd den = 1.0;
        for (int j = 0; j < 16; j++)
            if (j != i) den *= (cd(1.0, 0.0) - pd[j] * inv);
        cd r2 = 2.0 * numr / den;  // fold conjugate pair
        cd pm = 1.0;
        for (int k = 0; k < CM; k++) pm *= pd[i];
        if (n < NP) {
            C.pre[n] = pd[i].real(); C.pim[n] = pd[i].imag();
            C.rre[n] = r2.real();    C.rim[n] = r2.imag();
            C.pmre[n] = pm.real();   C.pmim[n] = pm.imag();
            n++;
        }
    }
    C.c0 = c0.real();
}

extern "C" void kernel_launch(void* const* d_in, const int* in_sizes, int n_in,
                              void* d_out, int out_size, void* d_ws, size_t ws_size,
                              hipStream_t stream) {
    const float* audio = (const float*)d_in[0];
    float* out = (float*)d_out;

    Coeffs C;
    compute_coeffs(C);

    // Workspace carve-up (~50.4 MB total):
    //   y1:    NB*LTOT floats   (33.6 MB) forward-pass output
    //   fst:   NC*NB*NP double2 ( 8.4 MB) per-chunk local final states
    //   carry: NC*NB*NP double2 ( 8.4 MB) per-chunk incoming states
    char* ws = (char*)d_ws;
    size_t y1_bytes = ((size_t)NB * LTOT * sizeof(float) + 255) & ~(size_t)255;
    size_t f_bytes  = (size_t)NC * NB * NP * sizeof(double2);
    float*   y1    = (float*)ws;
    double2* fst   = (double2*)(ws + y1_bytes);
    double2* carry = (double2*)(ws + y1_bytes + f_bytes);

    dim3 blk(256);
    dim3 grd((NC + 255) / 256, NB);

    // Pass A (forward filter on odd-extended input)
    k_states<0><<<grd, blk, 0, stream>>>(audio, y1, fst, C);
    k_scan<<<1, 256, 0, stream>>>(fst, carry, C);
    k_apply<0><<<grd, blk, 0, stream>>>(audio, y1, y1, carry, C);
    // Pass B (filter the reversed forward output; write reversed+trimmed out)
    k_states<1><<<grd, blk, 0, stream>>>(audio, y1, fst, C);
    k_scan<<<1, 256, 0, stream>>>(fst, carry, C);
    k_apply<1><<<grd, blk, 0, stream>>>(audio, y1, out, carry, C);
}

// Round 2
// 223.924 us; speedup vs baseline: 4.8592x; 4.8592x over previous
//
#include <hip/hip_runtime.h>
#include <cmath>
#include <complex>

// Problem constants: sr=16000, band 500-7000, order 8 -> 16 poles (8 conj pairs).
#define NB   32
#define LX   262144
#define PAD  51                       // padlen = 3*17
#define LTOT (LX + 2 * PAD)           // 262246
#define CM   64                       // chunk length (samples)
#define NC   ((LTOT + CM - 1) / CM)   // 4098 chunks per row
#define NP   8                        // conjugate-pair pole count
#define CPB  256                      // chunks per block (== threads)
#define BPR  ((NC + CPB - 1) / CPB)   // 17 blocks per row
#define TS   16                       // samples staged per stage
#define NSTG (CM / TS)                // 4 stages per chunk
#define JSEG ((NC + 255) / 256)       // 17 chunks per scan-thread

struct Coeffs {
    double pre[NP], pim[NP];    // poles (Im>0 half)
    double rre[NP], rim[NP];    // 2*residue (conjugate folded)
    double c0;                  // direct term
};
struct ScanC {
    double pmre[NP], pmim[NP];      // p^CM
    double qre[8][NP], qim[8][NP];  // (p^(CM*JSEG))^(2^k), k=0..7
};

// ---------------------------------------------------------------------------
// Staging: compute u[t] (ext value minus ext[0]) as f32 into LDS tile.
// PASS 0: odd-extended audio.  PASS 1: y1r (already reversed fwd output).
template <int PASS>
__device__ __forceinline__ void stage_tile(const float* __restrict__ x,
                                           const float* __restrict__ yr,
                                           double base, int S0, int st,
                                           float* __restrict__ tile) {
    for (int k = 0; k < TS; ++k) {
        int l  = threadIdx.x + CPB * k;   // 0..4095
        int tl = l / TS, il = l % TS;
        int t  = S0 + tl * CM + st * TS + il;
        float v = 0.f;
        if (t < LTOT) {
            if (PASS == 0) {
                double e;
                if (t < PAD)            e = 2.0 * (double)x[0] - (double)x[PAD - t];
                else if (t < PAD + LX)  e = (double)x[t - PAD];
                else                    e = 2.0 * (double)x[LX - 1] - (double)x[2 * LX + PAD - 2 - t];
                v = (float)(e - base);
            } else {
                v = (float)((double)yr[t] - base);
            }
        }
        tile[tl * (TS + 1) + il] = v;
    }
}

// K1: per-chunk local recurrence from zero state; emit final states
// fst layout: [seq][c], seq = b*NP + pole  (coalesced writes & scan reads)
template <int PASS>
__global__ __launch_bounds__(256) void k_states(const float* __restrict__ audio,
                                                const float* __restrict__ y1r,
                                                double2* __restrict__ fst, Coeffs C) {
    int rb = blockIdx.x, b = blockIdx.y, tid = threadIdx.x;
    const float* x  = audio + (size_t)b * LX;
    const float* yr = y1r + (size_t)b * LTOT;
    double base = (PASS == 0) ? (2.0 * (double)x[0] - (double)x[PAD]) : (double)yr[0];
    __shared__ float tile[CPB * (TS + 1)];
    int S0 = rb * CPB * CM;
    int c  = rb * CPB + tid;
    bool active = c < NC;
    double sre[NP], sim[NP];
#pragma unroll
    for (int q = 0; q < NP; q++) { sre[q] = 0.0; sim[q] = 0.0; }
    for (int st = 0; st < NSTG; ++st) {
        __syncthreads();
        stage_tile<PASS>(x, yr, base, S0, st, tile);
        __syncthreads();
        if (active) {
            for (int i = 0; i < TS; ++i) {
                double u = (double)tile[tid * (TS + 1) + i];
#pragma unroll
                for (int q = 0; q < NP; q++) {
                    double nre = fma(C.pre[q], sre[q], fma(-C.pim[q], sim[q], C.rre[q] * u));
                    double nim = fma(C.pre[q], sim[q], fma( C.pim[q], sre[q], C.rim[q] * u));
                    sre[q] = nre; sim[q] = nim;
                }
            }
        }
    }
    if (active) {
#pragma unroll
        for (int q = 0; q < NP; q++)
            fst[(size_t)(b * NP + q) * NC + c] = make_double2(sre[q], sim[q]);
    }
}

// K2: parallel affine scan over chunks. One block per (row,pole) sequence.
// In-place: fst -> carry (state entering each chunk).
__global__ __launch_bounds__(256) void k_scan(double2* __restrict__ fc, ScanC S) {
    int blk = blockIdx.x;          // seq = b*NP + i
    int i   = blk % NP;
    int t   = threadIdx.x;
    double pre = S.pmre[i], pim = S.pmim[i];
    double2* f = fc + (size_t)blk * NC;
    // thread-local segment combine: F_t over chunks [t*J, t*J+J)
    double sre = 0.0, sim = 0.0;
    for (int j = 0; j < JSEG; ++j) {
        int c = t * JSEG + j;
        if (c < NC) {
            double2 v = f[c];
            double nre = fma(pre, sre, fma(-pim, sim, v.x));
            double nim = fma(pre, sim, fma( pim, sre, v.y));
            sre = nre; sim = nim;
        }
    }
    __shared__ double2 sc[256];
    sc[t] = make_double2(sre, sim);
    __syncthreads();
#pragma unroll
    for (int k = 0; k < 8; ++k) {
        int d = 1 << k;
        double2 o = (t >= d) ? sc[t - d] : make_double2(0.0, 0.0);
        __syncthreads();
        if (t >= d) {
            double qr = S.qre[k][i], qi = S.qim[k][i];
            sre = qr * o.x - qi * o.y + sre;
            sim = qr * o.y + qi * o.x + sim;
        }
        sc[t] = make_double2(sre, sim);
        __syncthreads();
    }
    double2 e = (t == 0) ? make_double2(0.0, 0.0) : sc[t - 1];  // exclusive
    double s2re = e.x, s2im = e.y;
    for (int j = 0; j < JSEG; ++j) {
        int c = t * JSEG + j;
        if (c < NC) {
            double2 v = f[c];
            f[c] = make_double2(s2re, s2im);   // carry entering chunk c
            double nre = fma(pre, s2re, fma(-pim, s2im, v.x));
            double nim = fma(pre, s2im, fma( pim, s2re, v.y));
            s2re = nre; s2im = nim;
        }
    }
}

// K3: replay chunk with correct incoming state; emit filtered samples.
// PASS 0 -> y1r REVERSED (so pass B reads forward). PASS 1 -> d_out (rev+trim).
template <int PASS>
__global__ __launch_bounds__(256) void k_apply(const float* __restrict__ audio,
                                               const float* __restrict__ y1r,
                                               float* __restrict__ yout,
                                               const double2* __restrict__ carry, Coeffs C) {
    int rb = blockIdx.x, b = blockIdx.y, tid = threadIdx.x;
    const float* x  = audio + (size_t)b * LX;
    const float* yr = y1r + (size_t)b * LTOT;
    double base = (PASS == 0) ? (2.0 * (double)x[0] - (double)x[PAD]) : (double)yr[0];
    __shared__ float tile[CPB * (TS + 1)];
    int S0 = rb * CPB * CM;
    int c  = rb * CPB + tid;
    bool active = c < NC;
    double sre[NP], sim[NP];
#pragma unroll
    for (int q = 0; q < NP; q++) {
        double2 s0 = active ? carry[(size_t)(b * NP + q) * NC + c] : make_double2(0.0, 0.0);
        sre[q] = s0.x; sim[q] = s0.y;
    }
    for (int st = 0; st < NSTG; ++st) {
        __syncthreads();
        stage_tile<PASS>(x, yr, base, S0, st, tile);
        __syncthreads();
        for (int i = 0; i < TS; ++i) {
            double u = (double)tile[tid * (TS + 1) + i];
            double y = C.c0 * u;
#pragma unroll
            for (int q = 0; q < NP; q++) {
                double nre = fma(C.pre[q], sre[q], fma(-C.pim[q], sim[q], C.rre[q] * u));
                double nim = fma(C.pre[q], sim[q], fma( C.pim[q], sre[q], C.rim[q] * u));
                sre[q] = nre; sim[q] = nim;
                y += nre;
            }
            tile[tid * (TS + 1) + i] = (float)y;   // in-place: own row only
        }
        __syncthreads();
        // cooperative coalesced-ish store of the y tile
        for (int k = 0; k < TS; ++k) {
            int l  = tid + CPB * k;
            int tl = l / TS, il = l % TS;
            int t  = S0 + tl * CM + st * TS + il;
            float v = tile[tl * (TS + 1) + il];
            if (PASS == 0) {
                if (t < LTOT) yout[(size_t)b * LTOT + (LTOT - 1 - t)] = v;  // reversed
            } else {
                int j = (LTOT - 1 - PAD) - t;     // un-reverse + trim
                if (j >= 0 && j < LX) yout[(size_t)b * LX + j] = v;
            }
        }
    }
}

// ---------------------------------------------------------------------------
// Host: scipy butter(8,[500,7000]/8000,'bandpass') -> poles/residues (f64).
static void compute_coeffs(Coeffs& C, ScanC& S) {
    using cd = std::complex<double>;
    const int N = 8;
    const double sr = 16000.0, lo = 500.0, hi = 7000.0;
    const double fs = 2.0;
    double w0 = 2.0 * fs * std::tan(M_PI * (2.0 * lo / sr) / fs);
    double w1 = 2.0 * fs * std::tan(M_PI * (2.0 * hi / sr) / fs);
    double bw = w1 - w0;
    double wo = std::sqrt(w0 * w1);
    cd pbp[16];
    for (int k = 0; k < N; k++) {
        int m = -N + 1 + 2 * k;
        cd pl = -std::exp(cd(0.0, M_PI * m / (2.0 * N)));
        pl *= bw / 2.0;
        cd s = std::sqrt(pl * pl - cd(wo * wo, 0.0));
        pbp[k]     = pl + s;
        pbp[k + N] = pl - s;
    }
    double kbp = std::pow(bw, (double)N);
    const double fs2 = 4.0;
    cd pd[16];
    cd denom = 1.0;
    for (int i = 0; i < 16; i++) {
        pd[i] = (cd(fs2, 0.0) + pbp[i]) / (cd(fs2, 0.0) - pbp[i]);
        denom *= (cd(fs2, 0.0) - pbp[i]);
    }
    double kd = kbp * std::real(cd(std::pow(fs2, 8.0), 0.0) / denom);
    cd prodp = 1.0;
    for (int i = 0; i < 16; i++) prodp *= pd[i];
    cd c0 = cd(kd, 0.0) / prodp;
    int n = 0;
    for (int i = 0; i < 16; i++) {
        if (pd[i].imag() <= 0.0) continue;
        cd inv = 1.0 / pd[i];
        cd t1 = cd(1.0, 0.0) - inv;
        cd t2 = cd(1.0, 0.0) + inv;
        cd numr = cd(kd, 0.0);
        for (int k = 0; k < 8; k++) numr *= t1;
        for (int k = 0; k < 8; k++) numr *= t2;
        cd den = 1.0;
        for (int j = 0; j < 16; j++)
            if (j != i) den *= (cd(1.0, 0.0) - pd[j] * inv);
        cd r2 = 2.0 * numr / den;
        cd pm = 1.0;
        for (int k = 0; k < CM; k++) pm *= pd[i];
        if (n < NP) {
            C.pre[n] = pd[i].real(); C.pim[n] = pd[i].imag();
            C.rre[n] = r2.real();    C.rim[n] = r2.imag();
            S.pmre[n] = pm.real();   S.pmim[n] = pm.imag();
            cd q = 1.0;
            for (int k = 0; k < JSEG; k++) q *= pm;   // pm^JSEG
            for (int k = 0; k < 8; k++) {
                S.qre[k][n] = q.real(); S.qim[k][n] = q.imag();
                q *= q;                               // q^(2^(k+1))
            }
            n++;
        }
    }
    C.c0 = c0.real();
}

extern "C" void kernel_launch(void* const* d_in, const int* in_sizes, int n_in,
                              void* d_out, int out_size, void* d_ws, size_t ws_size,
                              hipStream_t stream) {
    const float* audio = (const float*)d_in[0];
    float* out = (float*)d_out;

    Coeffs C; ScanC S;
    compute_coeffs(C, S);

    // Workspace (~50.4 MB): y1r (NB*LTOT f32, 33.6MB) + fst/carry in-place
    // (256 seq * NC double2, 16.8MB)
    char* ws = (char*)d_ws;
    size_t y1_bytes = ((size_t)NB * LTOT * sizeof(float) + 255) & ~(size_t)255;
    float*   y1r = (float*)ws;
    double2* fst = (double2*)(ws + y1_bytes);

    dim3 blk(256);
    dim3 grd(BPR, NB);

    // Pass A: forward filter of odd-extended input; y written reversed.
    k_states<0><<<grd, blk, 0, stream>>>(audio, y1r, fst, C);
    k_scan<<<dim3(NB * NP), blk, 0, stream>>>(fst, S);
    k_apply<0><<<grd, blk, 0, stream>>>(audio, y1r, y1r, fst, C);
    // Pass B: filter reversed sequence (read forward from y1r); write out.
    k_states<1><<<grd, blk, 0, stream>>>(audio, y1r, fst, C);
    k_scan<<<dim3(NB * NP), blk, 0, stream>>>(fst, S);
    k_apply<1><<<grd, blk, 0, stream>>>(audio, y1r, out, fst, C);
}

// Round 3
// 181.445 us; speedup vs baseline: 5.9968x; 1.2341x over previous
//
#include <hip/hip_runtime.h>
#include <cmath>
#include <complex>

// sr=16000, band 500-7000, order 8 -> 16 poles (8 conjugate pairs).
#define NB   32
#define LX   262144
#define PAD  51                       // padlen = 3*17
#define LTOT (LX + 2 * PAD)           // 262246
#define CM   32                       // chunk length
#define NC   8196                     // ceil(LTOT/CM); last chunk has 6 valid
#define LPAD (NC * CM)                // 262272 (26 pad slots at reversed head)
#define CPB  256
#define BPR  ((NC + CPB - 1) / CPB)   // 33
#define NP   8
#define JSEG ((NC + 255) / 256)       // 33 chunks per scan thread

struct CoeffsF { float pre[NP], pim[NP], rre[NP], rim[NP], c0; };
struct ScanF {
    float pmre[NP], pmim[NP];         // p^CM
    float qre[8][NP], qim[8][NP];     // (p^(CM*JSEG))^(2^k)
    float gre[NP], gim[NP];           // r2*(1-p^CM)/(1-p)  (base correction)
};

// u[t] = ext[t] - ext[0] for the forward pass (odd extension of audio).
template <typename X>
__device__ __forceinline__ void load_u_fwd(const float* __restrict__ x,
                                           float base, int t0, float (&u)[CM]) {
    if (t0 >= PAD && t0 + CM <= PAD + LX) {
        const float* xs = x + (t0 - PAD);
#pragma unroll
        for (int i = 0; i < CM; i++) u[i] = xs[i] - base;
    } else {
#pragma unroll
        for (int i = 0; i < CM; i++) {
            int t = t0 + i;
            float e;
            if (t < PAD)            e = 2.0f * x[0] - x[PAD - t];
            else if (t < PAD + LX)  e = x[t - PAD];
            else if (t < LTOT)      e = 2.0f * x[LX - 1] - x[2 * LX + PAD - 2 - t];
            else                    e = base;   // u=0 tail (harmless, last chunk)
            u[i] = e - base;
        }
    }
}

// K1: pass-A local states from zero init. fst layout [seq=b*NP+q][c].
__global__ __launch_bounds__(256, 4) void k_statesA(const float* __restrict__ audio,
                                                    float2* __restrict__ fst, CoeffsF C) {
    int c = blockIdx.x * CPB + threadIdx.x, b = blockIdx.y;
    if (c >= NC) return;
    const float* x = audio + (size_t)b * LX;
    float base = 2.0f * x[0] - x[PAD];
    float u[CM];
    load_u_fwd<float>(x, base, c * CM, u);
    float sre[NP], sim[NP];
#pragma unroll
    for (int q = 0; q < NP; q++) { sre[q] = 0.f; sim[q] = 0.f; }
#pragma unroll
    for (int i = 0; i < CM; i++) {
        float uu = u[i];
#pragma unroll
        for (int q = 0; q < NP; q++) {
            float nre = fmaf(C.pre[q], sre[q], fmaf(-C.pim[q], sim[q], C.rre[q] * uu));
            float nim = fmaf(C.pre[q], sim[q], fmaf( C.pim[q], sre[q], C.rim[q] * uu));
            sre[q] = nre; sim[q] = nim;
        }
    }
#pragma unroll
    for (int q = 0; q < NP; q++)
        fst[(size_t)(b * NP + q) * NC + c] = make_float2(sre[q], sim[q]);
}

// K2: hierarchical affine scan, in-place fst -> carries. CORR: subtract
// base*G from each local state (pass B only; base = y[LTOT-1] = ybuf[26]).
template <int CORR>
__global__ __launch_bounds__(256) void k_scan(float2* __restrict__ fc,
                                              const float* __restrict__ ybuf, ScanF S) {
    int blk = blockIdx.x, q = blk % NP, b = blk / NP, t = threadIdx.x;
    float pre = S.pmre[q], pim = S.pmim[q];
    float cgr = 0.f, cgi = 0.f;
    if (CORR) {
        float base = ybuf[(size_t)b * LPAD + 26];
        cgr = base * S.gre[q]; cgi = base * S.gim[q];
    }
    float2* f = fc + (size_t)blk * NC;
    float sre = 0.f, sim = 0.f;
    for (int j = 0; j < JSEG; j++) {
        int c = t * JSEG + j;
        if (c < NC) {
            float2 v = f[c];
            float nre = fmaf(pre, sre, fmaf(-pim, sim, v.x - cgr));
            float nim = fmaf(pre, sim, fmaf( pim, sre, v.y - cgi));
            sre = nre; sim = nim;
        }
    }
    __shared__ float2 sc[256];
    sc[t] = make_float2(sre, sim);
    __syncthreads();
#pragma unroll
    for (int k = 0; k < 8; k++) {
        int d = 1 << k;
        float2 o = (t >= d) ? sc[t - d] : make_float2(0.f, 0.f);
        __syncthreads();
        if (t >= d) {
            float qr = S.qre[k][q], qi = S.qim[k][q];
            sre = fmaf(qr, o.x, fmaf(-qi, o.y, sre));
            sim = fmaf(qr, o.y, fmaf( qi, o.x, sim));
        }
        sc[t] = make_float2(sre, sim);
        __syncthreads();
    }
    float2 e = (t == 0) ? make_float2(0.f, 0.f) : sc[t - 1];
    float s2re = e.x, s2im = e.y;
    for (int j = 0; j < JSEG; j++) {
        int c = t * JSEG + j;
        if (c < NC) {
            float2 v = f[c];
            f[c] = make_float2(s2re, s2im);      // carry entering chunk c
            float nre = fmaf(pre, s2re, fmaf(-pim, s2im, v.x - cgr));
            float nim = fmaf(pre, s2im, fmaf( pim, s2re, v.y - cgi));
            s2re = nre; s2im = nim;
        }
    }
}

// K3: pass-A replay with carries -> y, written REVERSED into padded ybuf:
// ybuf[k] = y[LTOT-1-(k-26)], k=26..LPAD-1; k<26 pad (garbage, guarded later).
__global__ __launch_bounds__(256, 4) void k_applyA(const float* __restrict__ audio,
                                                   const float2* __restrict__ carry,
                                                   float* __restrict__ ybuf, CoeffsF C) {
    int c = blockIdx.x * CPB + threadIdx.x, b = blockIdx.y;
    if (c >= NC) return;
    const float* x = audio + (size_t)b * LX;
    float base = 2.0f * x[0] - x[PAD];
    float u[CM];
    load_u_fwd<float>(x, base, c * CM, u);
    float sre[NP], sim[NP];
#pragma unroll
    for (int q = 0; q < NP; q++) {
        float2 s0 = carry[(size_t)(b * NP + q) * NC + c];
        sre[q] = s0.x; sim[q] = s0.y;
    }
    float yv[CM];
#pragma unroll
    for (int i = 0; i < CM; i++) {
        float uu = u[i];
        float y = C.c0 * uu;
#pragma unroll
        for (int q = 0; q < NP; q++) {
            float nre = fmaf(C.pre[q], sre[q], fmaf(-C.pim[q], sim[q], C.rre[q] * uu));
            float nim = fmaf(C.pre[q], sim[q], fmaf( C.pim[q], sre[q], C.rim[q] * uu));
            sre[q] = nre; sim[q] = nim;
            y += nre;
        }
        yv[i] = y;
    }
    float* yb = ybuf + (size_t)b * LPAD + (size_t)(NC - 1 - c) * CM;
#pragma unroll
    for (int m = 0; m < CM / 4; m++) {
        float4 v = make_float4(yv[CM - 1 - 4 * m], yv[CM - 2 - 4 * m],
                               yv[CM - 3 - 4 * m], yv[CM - 4 - 4 * m]);
        *reinterpret_cast<float4*>(yb + 4 * m) = v;
    }
}

// K4: pass-B local states from raw reversed y (base handled in scan<1>).
__global__ __launch_bounds__(256, 4) void k_statesB(const float* __restrict__ ybuf,
                                                    float2* __restrict__ fst, CoeffsF C) {
    int cp = blockIdx.x * CPB + threadIdx.x, b = blockIdx.y;
    if (cp >= NC) return;
    const float* yb = ybuf + (size_t)b * LPAD;
    float base = yb[26];
    float w[CM];
#pragma unroll
    for (int m = 0; m < CM / 4; m++) {
        float4 v = *reinterpret_cast<const float4*>(yb + (size_t)cp * CM + 4 * m);
        w[4 * m] = v.x; w[4 * m + 1] = v.y; w[4 * m + 2] = v.z; w[4 * m + 3] = v.w;
    }
    float sre[NP], sim[NP];
#pragma unroll
    for (int q = 0; q < NP; q++) { sre[q] = 0.f; sim[q] = 0.f; }
#pragma unroll
    for (int i = 0; i < CM; i++) {
        float in = (cp > 0 || i >= 26) ? w[i] : base;   // pad -> u=0 after corr
#pragma unroll
        for (int q = 0; q < NP; q++) {
            float nre = fmaf(C.pre[q], sre[q], fmaf(-C.pim[q], sim[q], C.rre[q] * in));
            float nim = fmaf(C.pre[q], sim[q], fmaf( C.pim[q], sre[q], C.rim[q] * in));
            sre[q] = nre; sim[q] = nim;
        }
    }
#pragma unroll
    for (int q = 0; q < NP; q++)
        fst[(size_t)(b * NP + q) * NC + cp] = make_float2(sre[q], sim[q]);
}

// K5: pass-B replay -> final output (un-reverse + trim PAD).
__global__ __launch_bounds__(256, 4) void k_applyB(const float* __restrict__ ybuf,
                                                   const float2* __restrict__ carry,
                                                   float* __restrict__ out, CoeffsF C) {
    int cp = blockIdx.x * CPB + threadIdx.x, b = blockIdx.y;
    if (cp >= NC) return;
    const float* yb = ybuf + (size_t)b * LPAD;
    float base = yb[26];
    float w[CM];
#pragma unroll
    for (int m = 0; m < CM / 4; m++) {
        float4 v = *reinterpret_cast<const float4*>(yb + (size_t)cp * CM + 4 * m);
        w[4 * m] = v.x; w[4 * m + 1] = v.y; w[4 * m + 2] = v.z; w[4 * m + 3] = v.w;
    }
    float sre[NP], sim[NP];
#pragma unroll
    for (int q = 0; q < NP; q++) {
        float2 s0 = carry[(size_t)(b * NP + q) * NC + cp];
        sre[q] = s0.x; sim[q] = s0.y;
    }
    float* ob = out + (size_t)b * LX;
    int j0 = (LTOT - 1 - PAD + 26) - cp * CM;   // 262220 - 32*cp
#pragma unroll
    for (int i = 0; i < CM; i++) {
        float uu = (cp > 0 || i >= 26) ? (w[i] - base) : 0.f;
        float y = C.c0 * uu;
#pragma unroll
        for (int q = 0; q < NP; q++) {
            float nre = fmaf(C.pre[q], sre[q], fmaf(-C.pim[q], sim[q], C.rre[q] * uu));
            float nim = fmaf(C.pre[q], sim[q], fmaf( C.pim[q], sre[q], C.rim[q] * uu));
            sre[q] = nre; sim[q] = nim;
            y += nre;
        }
        int j = j0 - i;
        if (j >= 0 && j < LX) ob[j] = y;
    }
}

// Host: scipy butter(8,[500,7000]/8000,'bandpass') -> poles/residues (f64),
// cast to f32 coefficient structs.
static void compute_coeffs(CoeffsF& C, ScanF& S) {
    using cd = std::complex<double>;
    const int N = 8;
    const double sr = 16000.0, lo = 500.0, hi = 7000.0, fs = 2.0;
    double w0 = 2.0 * fs * std::tan(M_PI * (2.0 * lo / sr) / fs);
    double w1 = 2.0 * fs * std::tan(M_PI * (2.0 * hi / sr) / fs);
    double bw = w1 - w0, wo = std::sqrt(w0 * w1);
    cd pbp[16];
    for (int k = 0; k < N; k++) {
        int m = -N + 1 + 2 * k;
        cd pl = -std::exp(cd(0.0, M_PI * m / (2.0 * N)));
        pl *= bw / 2.0;
        cd s = std::sqrt(pl * pl - cd(wo * wo, 0.0));
        pbp[k] = pl + s; pbp[k + N] = pl - s;
    }
    double kbp = std::pow(bw, (double)N);
    const double fs2 = 4.0;
    cd pd[16], denom = 1.0;
    for (int i = 0; i < 16; i++) {
        pd[i] = (cd(fs2, 0.0) + pbp[i]) / (cd(fs2, 0.0) - pbp[i]);
        denom *= (cd(fs2, 0.0) - pbp[i]);
    }
    double kd = kbp * std::real(cd(std::pow(fs2, 8.0), 0.0) / denom);
    cd prodp = 1.0;
    for (int i = 0; i < 16; i++) prodp *= pd[i];
    cd c0 = cd(kd, 0.0) / prodp;
    int n = 0;
    for (int i = 0; i < 16; i++) {
        if (pd[i].imag() <= 0.0) continue;
        cd inv = 1.0 / pd[i];
        cd t1 = cd(1.0, 0.0) - inv, t2 = cd(1.0, 0.0) + inv;
        cd numr = cd(kd, 0.0);
        for (int k = 0; k < 8; k++) numr *= t1;
        for (int k = 0; k < 8; k++) numr *= t2;
        cd den = 1.0;
        for (int j = 0; j < 16; j++)
            if (j != i) den *= (cd(1.0, 0.0) - pd[j] * inv);
        cd r2 = 2.0 * numr / den;                     // conjugate-pair folded
        cd pm = 1.0;
        for (int k = 0; k < CM; k++) pm *= pd[i];     // p^CM
        cd G = r2 * (cd(1.0, 0.0) - pm) / (cd(1.0, 0.0) - pd[i]);
        if (n < NP) {
            C.pre[n] = (float)pd[i].real(); C.pim[n] = (float)pd[i].imag();
            C.rre[n] = (float)r2.real();    C.rim[n] = (float)r2.imag();
            S.pmre[n] = (float)pm.real();   S.pmim[n] = (float)pm.imag();
            S.gre[n] = (float)G.real();     S.gim[n] = (float)G.imag();
            cd qv = 1.0;
            for (int k = 0; k < JSEG; k++) qv *= pm;  // p^(CM*JSEG)
            for (int k = 0; k < 8; k++) {
                S.qre[k][n] = (float)qv.real(); S.qim[k][n] = (float)qv.imag();
                qv *= qv;
            }
            n++;
        }
    }
    C.c0 = (float)c0.real();
}

extern "C" void kernel_launch(void* const* d_in, const int* in_sizes, int n_in,
                              void* d_out, int out_size, void* d_ws, size_t ws_size,
                              hipStream_t stream) {
    const float* audio = (const float*)d_in[0];
    float* out = (float*)d_out;

    CoeffsF C; ScanF S;
    compute_coeffs(C, S);

    // ws: ybuf (NB*LPAD f32, 33.57MB, 16B-aligned blocks) + fst (256*NC f32x2,
    // 16.79MB, reused for both passes' states/carries in-place). Total 50.36MB.
    char* ws = (char*)d_ws;
    size_t ybytes = (size_t)NB * LPAD * sizeof(float);   // already 256-aligned
    float*  ybuf = (float*)ws;
    float2* fst  = (float2*)(ws + ybytes);

    dim3 blk(256), g(BPR, NB), gs(NB * NP);

    k_statesA<<<g,  blk, 0, stream>>>(audio, fst, C);
    k_scan<0> <<<gs, blk, 0, stream>>>(fst, ybuf, S);
    k_applyA <<<g,  blk, 0, stream>>>(audio, fst, ybuf, C);
    k_statesB<<<g,  blk, 0, stream>>>(ybuf, fst, C);
    k_scan<1> <<<gs, blk, 0, stream>>>(fst, ybuf, S);
    k_applyB <<<g,  blk, 0, stream>>>(ybuf, fst, out, C);
}

// Round 4
// 154.246 us; speedup vs baseline: 7.0542x; 1.1763x over previous
//
#include <hip/hip_runtime.h>
#include <cmath>
#include <complex>

// sr=16000, band 500-7000, order 8 -> 16 poles (8 conjugate pairs).
#define NB   32
#define LX   262144
#define PAD  51                       // padlen = 3*17
#define LTOT (LX + 2 * PAD)           // 262246
#define CM   32                       // chunk length
#define NC   8196                     // ceil(LTOT/CM)
#define LPAD (NC * CM)                // 262272 (26 pad slots at reversed head)
#define CPB  256
#define BPR  ((NC + CPB - 1) / CPB)   // 33
#define NP   8
#define JSEG ((NC + 255) / 256)       // 33 chunks per scan thread

struct CoeffsF { float pre[NP], pim[NP], rre[NP], rim[NP], c0; };
struct ScanF {
    float pmre[NP], pmim[NP];         // p^CM
    float qre[8][NP], qim[8][NP];     // (p^(CM*JSEG))^(2^k)
    float gre[NP], gim[NP];           // r2*(1-p^CM)/(1-p)  (base correction)
};

// u[t] = ext[t] - ext[0] for the forward pass (odd extension of audio).
__device__ __forceinline__ void load_u_fwd(const float* __restrict__ x,
                                           float base, int t0, float (&u)[CM]) {
    if (t0 >= PAD && t0 + CM <= PAD + LX) {
        const float* xs = x + (t0 - PAD);
#pragma unroll
        for (int m = 0; m < CM / 4; m++) {
            float4 v = *reinterpret_cast<const float4*>(xs + 4 * m);
            u[4 * m] = v.x - base; u[4 * m + 1] = v.y - base;
            u[4 * m + 2] = v.z - base; u[4 * m + 3] = v.w - base;
        }
    } else {
#pragma unroll
        for (int i = 0; i < CM; i++) {
            int t = t0 + i;
            float e;
            if (t < PAD)            e = 2.0f * x[0] - x[PAD - t];
            else if (t < PAD + LX)  e = x[t - PAD];
            else if (t < LTOT)      e = 2.0f * x[LX - 1] - x[2 * LX + PAD - 2 - t];
            else                    e = base;   // u=0 tail continuation
            u[i] = e - base;
        }
    }
}

// K1: pass-A local states from zero init. fst layout [seq=b*NP+q][c].
__global__ __launch_bounds__(256, 4) void k_statesA(const float* __restrict__ audio,
                                                    float2* __restrict__ fst, CoeffsF C) {
    int c = blockIdx.x * CPB + threadIdx.x, b = blockIdx.y;
    if (c >= NC) return;
    const float* x = audio + (size_t)b * LX;
    float base = 2.0f * x[0] - x[PAD];
    float u[CM];
    load_u_fwd(x, base, c * CM, u);
    float sre[NP], sim[NP];
#pragma unroll
    for (int q = 0; q < NP; q++) { sre[q] = 0.f; sim[q] = 0.f; }
#pragma unroll
    for (int i = 0; i < CM; i++) {
        float uu = u[i];
#pragma unroll
        for (int q = 0; q < NP; q++) {
            float nre = fmaf(C.pre[q], sre[q], fmaf(-C.pim[q], sim[q], C.rre[q] * uu));
            float nim = fmaf(C.pre[q], sim[q], fmaf( C.pim[q], sre[q], C.rim[q] * uu));
            sre[q] = nre; sim[q] = nim;
        }
    }
#pragma unroll
    for (int q = 0; q < NP; q++)
        fst[(size_t)(b * NP + q) * NC + c] = make_float2(sre[q], sim[q]);
}

// K2: hierarchical affine scan, in-place states -> carries.
// CORR=1 (pass B): logical chunk idx maps to physical slot NC-1-idx, and
// base*G is subtracted from each local state (base = y[LTOT-1] = ybuf[26]).
template <int CORR>
__global__ __launch_bounds__(256) void k_scan(float2* __restrict__ fc,
                                              const float* __restrict__ ybuf, ScanF S) {
    int blk = blockIdx.x, q = blk % NP, b = blk / NP, t = threadIdx.x;
    float pre = S.pmre[q], pim = S.pmim[q];
    float cgr = 0.f, cgi = 0.f;
    if (CORR) {
        float base = ybuf[(size_t)b * LPAD + 26];
        cgr = base * S.gre[q]; cgi = base * S.gim[q];
    }
    float2* f = fc + (size_t)blk * NC;
    float sre = 0.f, sim = 0.f;
    for (int j = 0; j < JSEG; j++) {
        int c = t * JSEG + j;
        if (c < NC) {
            float2 v = f[CORR ? (NC - 1 - c) : c];
            float nre = fmaf(pre, sre, fmaf(-pim, sim, v.x - cgr));
            float nim = fmaf(pre, sim, fmaf( pim, sre, v.y - cgi));
            sre = nre; sim = nim;
        }
    }
    __shared__ float2 sc[256];
    sc[t] = make_float2(sre, sim);
    __syncthreads();
#pragma unroll
    for (int k = 0; k < 8; k++) {
        int d = 1 << k;
        float2 o = (t >= d) ? sc[t - d] : make_float2(0.f, 0.f);
        __syncthreads();
        if (t >= d) {
            float qr = S.qre[k][q], qi = S.qim[k][q];
            sre = fmaf(qr, o.x, fmaf(-qi, o.y, sre));
            sim = fmaf(qr, o.y, fmaf( qi, o.x, sim));
        }
        sc[t] = make_float2(sre, sim);
        __syncthreads();
    }
    float2 e = (t == 0) ? make_float2(0.f, 0.f) : sc[t - 1];
    float s2re = e.x, s2im = e.y;
    for (int j = 0; j < JSEG; j++) {
        int c = t * JSEG + j;
        if (c < NC) {
            int s = CORR ? (NC - 1 - c) : c;
            float2 v = f[s];
            f[s] = make_float2(s2re, s2im);      // carry entering logical chunk c
            float nre = fmaf(pre, s2re, fmaf(-pim, s2im, v.x - cgr));
            float nim = fmaf(pre, s2im, fmaf( pim, s2re, v.y - cgi));
            s2re = nre; s2im = nim;
        }
    }
}

// K3 (fused): pass-A replay with carryA -> y (written reversed into ybuf,
// aligned float4), PLUS pass-B local states computed from the register yv
// (reverse-order chunk recurrence) written in-place over carryA slot c.
// Thread c's forward chunk IS pass-B chunk cp = NC-1-c.
__global__ __launch_bounds__(256) void k_fusedA(const float* __restrict__ audio,
                                                float2* __restrict__ fst,
                                                float* __restrict__ ybuf, CoeffsF C) {
    int c = blockIdx.x * CPB + threadIdx.x, b = blockIdx.y;
    if (c >= NC) return;
    const float* x = audio + (size_t)b * LX;
    float base = 2.0f * x[0] - x[PAD];
    float buf[CM];
    load_u_fwd(x, base, c * CM, buf);
    float sre[NP], sim[NP];
#pragma unroll
    for (int q = 0; q < NP; q++) {
        float2 s0 = fst[(size_t)(b * NP + q) * NC + c];
        sre[q] = s0.x; sim[q] = s0.y;
    }
#pragma unroll
    for (int i = 0; i < CM; i++) {
        float uu = buf[i];
        float y = C.c0 * uu;
#pragma unroll
        for (int q = 0; q < NP; q++) {
            float nre = fmaf(C.pre[q], sre[q], fmaf(-C.pim[q], sim[q], C.rre[q] * uu));
            float nim = fmaf(C.pre[q], sim[q], fmaf( C.pim[q], sre[q], C.rim[q] * uu));
            sre[q] = nre; sim[q] = nim;
            y += nre;
        }
        buf[i] = y;   // in-place: buf now holds forward y values
    }
    // reversed aligned write: ybuf[(NC-1-c)*CM + i] = buf[31-i]
    float* yb = ybuf + (size_t)b * LPAD + (size_t)(NC - 1 - c) * CM;
#pragma unroll
    for (int m = 0; m < CM / 4; m++) {
        float4 v = make_float4(buf[CM - 1 - 4 * m], buf[CM - 2 - 4 * m],
                               buf[CM - 3 - 4 * m], buf[CM - 4 - 4 * m]);
        *reinterpret_cast<float4*>(yb + 4 * m) = v;
    }
    // pass-B local state for chunk cp=NC-1-c: recurrence over buf reversed.
    // For c==NC-1 (cp==0), pass-B samples i<26 are pad -> input := base2,
    // where base2 = y[LTOT-1] = buf[5] of this very thread.
    float tre[NP], tim[NP];
#pragma unroll
    for (int q = 0; q < NP; q++) { tre[q] = 0.f; tim[q] = 0.f; }
    float base2 = buf[5];
    bool last = (c == NC - 1);
#pragma unroll
    for (int i = 0; i < CM; i++) {
        float w = buf[CM - 1 - i];
        if (last && i < 26) w = base2;
#pragma unroll
        for (int q = 0; q < NP; q++) {
            float nre = fmaf(C.pre[q], tre[q], fmaf(-C.pim[q], tim[q], C.rre[q] * w));
            float nim = fmaf(C.pre[q], tim[q], fmaf( C.pim[q], tre[q], C.rim[q] * w));
            tre[q] = nre; tim[q] = nim;
        }
    }
#pragma unroll
    for (int q = 0; q < NP; q++)
        fst[(size_t)(b * NP + q) * NC + c] = make_float2(tre[q], tim[q]);
}

// K4: pass-B replay -> final output (un-reverse + trim), vectorized stores.
// carry for pass-B chunk cp lives at physical slot NC-1-cp.
__global__ __launch_bounds__(256) void k_applyB(const float* __restrict__ ybuf,
                                                const float2* __restrict__ carry,
                                                float* __restrict__ out, CoeffsF C) {
    int cp = blockIdx.x * CPB + threadIdx.x, b = blockIdx.y;
    if (cp >= NC) return;
    const float* yb = ybuf + (size_t)b * LPAD;
    float base = yb[26];
    float buf[CM];
#pragma unroll
    for (int m = 0; m < CM / 4; m++) {
        float4 v = *reinterpret_cast<const float4*>(yb + (size_t)cp * CM + 4 * m);
        buf[4 * m] = v.x; buf[4 * m + 1] = v.y;
        buf[4 * m + 2] = v.z; buf[4 * m + 3] = v.w;
    }
    float sre[NP], sim[NP];
#pragma unroll
    for (int q = 0; q < NP; q++) {
        float2 s0 = carry[(size_t)(b * NP + q) * NC + (NC - 1 - cp)];
        sre[q] = s0.x; sim[q] = s0.y;
    }
#pragma unroll
    for (int i = 0; i < CM; i++) {
        float uu = buf[i] - base;     // cp==0 pad garbage -> outputs OOB anyway
        float y = C.c0 * uu;
#pragma unroll
        for (int q = 0; q < NP; q++) {
            float nre = fmaf(C.pre[q], sre[q], fmaf(-C.pim[q], sim[q], C.rre[q] * uu));
            float nim = fmaf(C.pre[q], sim[q], fmaf( C.pim[q], sre[q], C.rim[q] * uu));
            sre[q] = nre; sim[q] = nim;
            y += nre;
        }
        buf[i] = y;
    }
    // out[j] = buf[i], j = 262220 - 32*cp - i; window [jb, jb+31], jb==1 mod 4
    float* ob = out + (size_t)b * LX;
    int jb = (LTOT - 1 - PAD + 26 - 31) - cp * CM;   // 262189 - 32*cp
    if (jb >= 0 && jb + 31 < LX) {
        ob[jb] = buf[31]; ob[jb + 1] = buf[30]; ob[jb + 2] = buf[29];
        ob[jb + 31] = buf[0];
#pragma unroll
        for (int g = 0; g < 7; g++) {
            float4 v = make_float4(buf[28 - 4 * g], buf[27 - 4 * g],
                                   buf[26 - 4 * g], buf[25 - 4 * g]);
            *reinterpret_cast<float4*>(ob + jb + 3 + 4 * g) = v;
        }
    } else {
#pragma unroll
        for (int i = 0; i < CM; i++) {
            int j = jb + 31 - i;
            if (j >= 0 && j < LX) ob[j] = buf[i];
        }
    }
}

// Host: scipy butter(8,[500,7000]/8000,'bandpass') -> poles/residues (f64),
// cast to f32 coefficient structs.
static void compute_coeffs(CoeffsF& C, ScanF& S) {
    using cd = std::complex<double>;
    const int N = 8;
    const double sr = 16000.0, lo = 500.0, hi = 7000.0, fs = 2.0;
    double w0 = 2.0 * fs * std::tan(M_PI * (2.0 * lo / sr) / fs);
    double w1 = 2.0 * fs * std::tan(M_PI * (2.0 * hi / sr) / fs);
    double bw = w1 - w0, wo = std::sqrt(w0 * w1);
    cd pbp[16];
    for (int k = 0; k < N; k++) {
        int m = -N + 1 + 2 * k;
        cd pl = -std::exp(cd(0.0, M_PI * m / (2.0 * N)));
        pl *= bw / 2.0;
        cd s = std::sqrt(pl * pl - cd(wo * wo, 0.0));
        pbp[k] = pl + s; pbp[k + N] = pl - s;
    }
    double kbp = std::pow(bw, (double)N);
    const double fs2 = 4.0;
    cd pd[16], denom = 1.0;
    for (int i = 0; i < 16; i++) {
        pd[i] = (cd(fs2, 0.0) + pbp[i]) / (cd(fs2, 0.0) - pbp[i]);
        denom *= (cd(fs2, 0.0) - pbp[i]);
    }
    double kd = kbp * std::real(cd(std::pow(fs2, 8.0), 0.0) / denom);
    cd prodp = 1.0;
    for (int i = 0; i < 16; i++) prodp *= pd[i];
    cd c0 = cd(kd, 0.0) / prodp;
    int n = 0;
    for (int i = 0; i < 16; i++) {
        if (pd[i].imag() <= 0.0) continue;
        cd inv = 1.0 / pd[i];
        cd t1 = cd(1.0, 0.0) - inv, t2 = cd(1.0, 0.0) + inv;
        cd numr = cd(kd, 0.0);
        for (int k = 0; k < 8; k++) numr *= t1;
        for (int k = 0; k < 8; k++) numr *= t2;
        cd den = 1.0;
        for (int j = 0; j < 16; j++)
            if (j != i) den *= (cd(1.0, 0.0) - pd[j] * inv);
        cd r2 = 2.0 * numr / den;                     // conjugate-pair folded
        cd pm = 1.0;
        for (int k = 0; k < CM; k++) pm *= pd[i];     // p^CM
        cd G = r2 * (cd(1.0, 0.0) - pm) / (cd(1.0, 0.0) - pd[i]);
        if (n < NP) {
            C.pre[n] = (float)pd[i].real(); C.pim[n] = (float)pd[i].imag();
            C.rre[n] = (float)r2.real();    C.rim[n] = (float)r2.imag();
            S.pmre[n] = (float)pm.real();   S.pmim[n] = (float)pm.imag();
            S.gre[n] = (float)G.real();     S.gim[n] = (float)G.imag();
            cd qv = 1.0;
            for (int k = 0; k < JSEG; k++) qv *= pm;  // p^(CM*JSEG)
            for (int k = 0; k < 8; k++) {
                S.qre[k][n] = (float)qv.real(); S.qim[k][n] = (float)qv.imag();
                qv *= qv;
            }
            n++;
        }
    }
    C.c0 = (float)c0.real();
}

extern "C" void kernel_launch(void* const* d_in, const int* in_sizes, int n_in,
                              void* d_out, int out_size, void* d_ws, size_t ws_size,
                              hipStream_t stream) {
    const float* audio = (const float*)d_in[0];
    float* out = (float*)d_out;

    CoeffsF C; ScanF S;
    compute_coeffs(C, S);

    // ws: ybuf (NB*LPAD f32, 33.57MB) + fst (256*NC float2, 16.79MB; holds
    // statesA -> carryA -> statesB -> carryB in-place). Total 50.36MB.
    char* ws = (char*)d_ws;
    size_t ybytes = (size_t)NB * LPAD * sizeof(float);
    float*  ybuf = (float*)ws;
    float2* fst  = (float2*)(ws + ybytes);

    dim3 blk(256), g(BPR, NB), gs(NB * NP);

    k_statesA<<<g,  blk, 0, stream>>>(audio, fst, C);
    k_scan<0> <<<gs, blk, 0, stream>>>(fst, ybuf, S);
    k_fusedA  <<<g,  blk, 0, stream>>>(audio, fst, ybuf, C);
    k_scan<1> <<<gs, blk, 0, stream>>>(fst, ybuf, S);
    k_applyB  <<<g,  blk, 0, stream>>>(ybuf, fst, out, C);
}